// Round 1
// baseline (540.810 us; speedup 1.0000x reference)
//
#include <hip/hip_runtime.h>
#include <hip/hip_bf16.h>
#include <math.h>

typedef unsigned short u16;
typedef __attribute__((ext_vector_type(8))) short bf16x8;   // 8 bf16 = 4 VGPRs
typedef __attribute__((ext_vector_type(4))) float f32x4;

#define MFMA16(a,b,c) __builtin_amdgcn_mfma_f32_16x16x32_bf16(a,b,c,0,0,0)

__device__ __forceinline__ u16 f2b(float f){
  unsigned u = __float_as_uint(f);
  u += 0x7fffu + ((u >> 16) & 1u);      // RNE
  return (u16)(u >> 16);
}

// async global->LDS, 16B per lane; LDS dest = wave-uniform base + lane*16
__device__ __forceinline__ void gll16(const void* g, void* l){
  __builtin_amdgcn_global_load_lds(
      (__attribute__((address_space(1))) void*)(const_cast<void*>(g)),
      (__attribute__((address_space(3))) void*)l, 16, 0, 0);
}

// ---------------- conversions ----------------
__global__ __launch_bounds__(256) void conv_x_k(const float* __restrict__ x, u16* __restrict__ xb){
  size_t i = ((size_t)blockIdx.x*256 + threadIdx.x)*8;
  float4 a = *(const float4*)(x+i);
  float4 b = *(const float4*)(x+i+4);
  uint4 u;
  u.x = (unsigned)f2b(a.x) | ((unsigned)f2b(a.y)<<16);
  u.y = (unsigned)f2b(a.z) | ((unsigned)f2b(a.w)<<16);
  u.z = (unsigned)f2b(b.x) | ((unsigned)f2b(b.y)<<16);
  u.w = (unsigned)f2b(b.z) | ((unsigned)f2b(b.w)<<16);
  *(uint4*)(xb+i) = u;
}

// wqkvT[n][m], n = proj*1024 + h*128 + d  <-  w_proj[m, h, d]
__global__ __launch_bounds__(256) void conv_wqkvT_k(const float* __restrict__ wq,
    const float* __restrict__ wk, const float* __restrict__ wv, u16* __restrict__ wqkvT){
  unsigned tid = blockIdx.x*256 + threadIdx.x;      // 3*1024*1024 total
  unsigned n = tid >> 10, m = tid & 1023;
  unsigned proj = n >> 10, hd = n & 1023;
  const float* w = (proj==0) ? wq : (proj==1 ? wk : wv);
  wqkvT[tid] = f2b(w[(size_t)m*1024 + hd]);
}

// woT[m][hd] = wo[h][d][m]
__global__ __launch_bounds__(256) void conv_woT_k(const float* __restrict__ wo, u16* __restrict__ woT){
  unsigned tid = blockIdx.x*256 + threadIdx.x;      // 1M total
  unsigned m = tid >> 10, hd = tid & 1023;
  woT[tid] = f2b(wo[(size_t)hd*1024 + m]);
}

// ---------------- 128x128 bf16 GEMM mainloop, C = A[M][K] * B[N][K]^T ----------------
__device__ __forceinline__ void gemm128_bt(
    const u16* __restrict__ A, const u16* __restrict__ B, int K,
    int rowBase, int colBase, f32x4 acc[4][4])
{
  __shared__ __align__(16) u16 lA[128*32];
  __shared__ __align__(16) u16 lB[128*32];
  const int tid = threadIdx.x, lane = tid & 63, wave = tid >> 6;
  const int wr = wave >> 1, wc = wave & 1;
  const int qd = lane >> 4, c = lane & 15;

  // LDS frag offsets (XOR swizzle: slot = chunk ^ ((row>>1)&3)) — fixed across K loop
  int aOff[4], bOff[4];
#pragma unroll
  for (int mi=0;mi<4;mi++){ int row = wr*64 + mi*16 + c; aOff[mi] = row*32 + ((qd ^ ((row>>1)&3))*8); }
#pragma unroll
  for (int ni=0;ni<4;ni++){ int row = wc*64 + ni*16 + c; bOff[ni] = row*32 + ((qd ^ ((row>>1)&3))*8); }

  const u16* gA[2]; const u16* gB[2]; int seg[2];
#pragma unroll
  for (int c2=0;c2<2;c2++){
    int s = wave*2 + c2;
    int row = s*16 + (lane>>2);
    int gch = (lane&3) ^ ((row>>1)&3);
    gA[c2] = A + (size_t)(rowBase+row)*K + gch*8;
    gB[c2] = B + (size_t)(colBase+row)*K + gch*8;
    seg[c2] = s*512;
  }
#pragma unroll
  for (int mi=0;mi<4;mi++)
#pragma unroll
    for (int ni=0;ni<4;ni++)
#pragma unroll
      for (int e=0;e<4;e++) acc[mi][ni][e]=0.f;

  for (int k0=0; k0<K; k0+=32){
#pragma unroll
    for (int c2=0;c2<2;c2++){
      gll16(gA[c2] + k0, &lA[seg[c2]]);
      gll16(gB[c2] + k0, &lB[seg[c2]]);
    }
    __syncthreads();
    bf16x8 af[4], bb[4];
#pragma unroll
    for (int mi=0;mi<4;mi++) af[mi] = *(const bf16x8*)(lA + aOff[mi]);
#pragma unroll
    for (int ni=0;ni<4;ni++) bb[ni] = *(const bf16x8*)(lB + bOff[ni]);
#pragma unroll
    for (int ni=0;ni<4;ni++)
#pragma unroll
      for (int mi=0;mi<4;mi++)
        acc[mi][ni] = MFMA16(af[mi], bb[ni], acc[mi][ni]);
    __syncthreads();
  }
}

// ---------------- QKV GEMM + RoPE epilogue ----------------
__global__ __launch_bounds__(256) void gemm_qkv_k(
    const u16* __restrict__ xb, const u16* __restrict__ wqkvT,
    u16* __restrict__ q, u16* __restrict__ k, u16* __restrict__ vT)
{
  f32x4 acc[4][4];
  const int rowBase = blockIdx.x*128, colBase = blockIdx.y*128;
  gemm128_bt(xb, wqkvT, 1024, rowBase, colBase, acc);
  const int tid = threadIdx.x, lane = tid & 63, wave = tid >> 6;
  const int wr = wave >> 1, wc = wave & 1;
  const int qd = lane >> 4, c = lane & 15;
  const int nb = blockIdx.y;
  const int proj = nb >> 3, h = nb & 7;

  if (proj < 2){
    u16* dst = (proj==0) ? q : k;
    if (wc == 0){
      // RoPE: d in [0,64): pairs (d, d+32); tiles (0,2) and (1,3)
      float ang0 = __powf(10000.0f, -(float)c      * (1.0f/32.0f));
      float ang1 = __powf(10000.0f, -(float)(c+16) * (1.0f/32.0f));
#pragma unroll
      for (int mi=0;mi<4;mi++){
#pragma unroll
        for (int r=0;r<4;r++){
          int row = rowBase + wr*64 + mi*16 + qd*4 + r;
          int b = row >> 11, t = row & 2047;
          long base = (((long)(b*8+h))*2048 + t)*128;
          float s0,c0,s1,c1;
          __sincosf((float)t*ang0, &s0, &c0);
          __sincosf((float)t*ang1, &s1, &c1);
          { float e = acc[mi][0][r], od = acc[mi][2][r];
            dst[base + c]      = f2b(e*c0 - od*s0);
            dst[base + c + 32] = f2b(e*s0 + od*c0); }
          { float e = acc[mi][1][r], od = acc[mi][3][r];
            dst[base + 16 + c]      = f2b(e*c1 - od*s1);
            dst[base + 16 + c + 32] = f2b(e*s1 + od*c1); }
        }
      }
    } else {
      // pass-through half d in [64,128)
#pragma unroll
      for (int mi=0;mi<4;mi++){
#pragma unroll
        for (int r=0;r<4;r++){
          int row = rowBase + wr*64 + mi*16 + qd*4 + r;
          int b = row >> 11, t = row & 2047;
          long base = (((long)(b*8+h))*2048 + t)*128 + 64;
#pragma unroll
          for (int ni=0;ni<4;ni++)
            dst[base + ni*16 + c] = f2b(acc[mi][ni][r]);
        }
      }
    }
  } else {
    // V: store transposed vT[(bh*128 + d)*2048 + t], 4 consecutive t per lane -> 8B store
#pragma unroll
    for (int mi=0;mi<4;mi++){
      int row0 = rowBase + wr*64 + mi*16 + qd*4;
      int b = row0 >> 11, t = row0 & 2047;
#pragma unroll
      for (int ni=0;ni<4;ni++){
        int d = wc*64 + ni*16 + c;
        long base = (((long)(b*8+h))*128 + d)*2048 + t;
        unsigned u0 = (unsigned)f2b(acc[mi][ni][0]) | ((unsigned)f2b(acc[mi][ni][1])<<16);
        unsigned u1 = (unsigned)f2b(acc[mi][ni][2]) | ((unsigned)f2b(acc[mi][ni][3])<<16);
        *(uint2*)(vT + base) = make_uint2(u0, u1);
      }
    }
  }
}

// ---------------- flash attention: 64 q-rows/block, 4 waves x 16 rows ----------------
__global__ __launch_bounds__(256) void attn_k(
    const u16* __restrict__ q, const u16* __restrict__ k,
    const u16* __restrict__ vT, u16* __restrict__ o)
{
  __shared__ __align__(16) u16 lK[64*128];     // [t][d], chunk-swizzled ^ (row&15)
  __shared__ __align__(16) u16 lV[128*64];     // [d][t], chunk-swizzled ^ (row&7)
  __shared__ __align__(16) u16 lP[4][16*64];   // per-wave P, [qrow][t], ^ (row&7)
  const int tid = threadIdx.x, lane = tid & 63, wave = tid >> 6;
  const int qd = lane >> 4, c = lane & 15;
  const int qt = blockIdx.x, bh = blockIdx.y;
  const int q0 = qt * 64;

  bf16x8 aQ[4];
  {
    const long qrow = (long)bh*2048 + q0 + wave*16 + c;
#pragma unroll
    for (int kk=0;kk<4;kk++)
      aQ[kk] = *(const bf16x8*)(q + qrow*128 + kk*32 + qd*8);
  }
  f32x4 accO[8];
#pragma unroll
  for (int i=0;i<8;i++)
#pragma unroll
    for (int e=0;e<4;e++) accO[i][e]=0.f;
  float m2[4], l[4];
#pragma unroll
  for (int r=0;r<4;r++){ m2[r] = -INFINITY; l[r] = 0.f; }
  const float sc = (1.0f/128.0f) * 1.44269504088896f;   // q,k each scaled D^-0.5 -> 1/128; log2e

  int kOff[4][4], vOff[8][2], pOff[2];
#pragma unroll
  for (int ni=0;ni<4;ni++){ int row=ni*16+c;
#pragma unroll
    for (int kk=0;kk<4;kk++){ int ch=kk*4+qd; kOff[ni][kk]=row*128 + ((ch^(row&15))*8); } }
#pragma unroll
  for (int di=0;di<8;di++){ int row=di*16+c;
#pragma unroll
    for (int kk=0;kk<2;kk++){ int ch=kk*4+qd; vOff[di][kk]=row*64 + ((ch^(row&7))*8); } }
#pragma unroll
  for (int kk=0;kk<2;kk++){ int ch=kk*4+qd; pOff[kk]=c*64 + ((ch^(c&7))*8); }

  for (int kt=0; kt<=qt; kt++){
#pragma unroll
    for (int cc=0; cc<4; cc++){
      int s = wave*4+cc;
      int row = s*4 + (lane>>4);
      int gch = (lane&15) ^ (row&15);
      gll16(k + ((long)bh*2048 + kt*64 + row)*128 + gch*8, &lK[s*512]);
    }
#pragma unroll
    for (int cc=0; cc<4; cc++){
      int s = wave*4+cc;
      int row = s*8 + (lane>>3);
      int gch = (lane&7) ^ (row&7);
      gll16(vT + ((long)bh*128 + row)*2048 + kt*64 + gch*8, &lV[s*512]);
    }
    __syncthreads();

    f32x4 accS[4];
#pragma unroll
    for (int ni=0;ni<4;ni++)
#pragma unroll
      for (int e=0;e<4;e++) accS[ni][e]=0.f;
#pragma unroll
    for (int kk=0;kk<4;kk++)
#pragma unroll
      for (int ni=0;ni<4;ni++){
        bf16x8 bk = *(const bf16x8*)(lK + kOff[ni][kk]);
        accS[ni] = MFMA16(aQ[kk], bk, accS[ni]);
      }

    if (kt == qt){
#pragma unroll
      for (int ni=0;ni<4;ni++){
        int col = kt*64 + ni*16 + c;
#pragma unroll
        for (int r=0;r<4;r++){
          int row = q0 + wave*16 + qd*4 + r;
          if (col > row) accS[ni][r] = -INFINITY;
        }
      }
    }

    float mNew[4], alpha[4];
#pragma unroll
    for (int r=0;r<4;r++){
      float v = fmaxf(fmaxf(accS[0][r],accS[1][r]), fmaxf(accS[2][r],accS[3][r]));
      v *= sc;
#pragma unroll
      for (int off=1; off<16; off<<=1) v = fmaxf(v, __shfl_xor(v, off));
      mNew[r] = fmaxf(m2[r], v);
      alpha[r] = exp2f(m2[r] - mNew[r]);
      m2[r] = mNew[r];
      l[r] *= alpha[r];
    }
    float pv[4][4];
#pragma unroll
    for (int ni=0;ni<4;ni++)
#pragma unroll
      for (int r=0;r<4;r++)
        pv[ni][r] = exp2f(accS[ni][r]*sc - mNew[r]);
#pragma unroll
    for (int r=0;r<4;r++){
      float s = pv[0][r]+pv[1][r]+pv[2][r]+pv[3][r];
#pragma unroll
      for (int off=1; off<16; off<<=1) s += __shfl_xor(s, off);
      l[r] += s;
    }
    // P -> LDS (A-operand re-layout), per-wave buffer, same-wave DS ordering
#pragma unroll
    for (int ni=0;ni<4;ni++){
      int col = ni*16 + c; int chb = col>>3; int cb = col&7;
#pragma unroll
      for (int r=0;r<4;r++){
        int prow = qd*4+r;
        lP[wave][prow*64 + ((chb^(prow&7))*8) + cb] = f2b(pv[ni][r]);
      }
    }
#pragma unroll
    for (int di=0;di<8;di++)
#pragma unroll
      for (int r=0;r<4;r++) accO[di][r] *= alpha[r];
#pragma unroll
    for (int kk=0;kk<2;kk++){
      bf16x8 ap = *(const bf16x8*)(&lP[wave][pOff[kk]]);
#pragma unroll
      for (int di=0;di<8;di++){
        bf16x8 bv = *(const bf16x8*)(lV + vOff[di][kk]);
        accO[di] = MFMA16(ap, bv, accO[di]);
      }
    }
    __syncthreads();
  }

  const int b = bh >> 3, h = bh & 7;
#pragma unroll
  for (int r=0;r<4;r++){
    int t = q0 + wave*16 + qd*4 + r;
    float inv = 1.0f / l[r];
    long base = (((long)b*2048 + t)*8 + h)*128;
#pragma unroll
    for (int di=0;di<8;di++)
      o[base + di*16 + c] = f2b(accO[di][r]*inv);
  }
}

// ---------------- output projection ----------------
__global__ __launch_bounds__(256) void gemm_out_k(
    const u16* __restrict__ oa, const u16* __restrict__ woT, float* __restrict__ out)
{
  f32x4 acc[4][4];
  const int rowBase = blockIdx.x*128, colBase = blockIdx.y*128;
  gemm128_bt(oa, woT, 1024, rowBase, colBase, acc);
  const int lane = threadIdx.x & 63, wave = threadIdx.x >> 6;
  const int wr = wave >> 1, wc = wave & 1;
  const int qd = lane >> 4, c = lane & 15;
#pragma unroll
  for (int mi=0;mi<4;mi++){
#pragma unroll
    for (int ni=0;ni<4;ni++){
      int row = rowBase + wr*64 + mi*16 + qd*4;
      int col = colBase + wc*64 + ni*16 + c;
#pragma unroll
      for (int r=0;r<4;r++)
        out[(size_t)(row+r)*1024 + col] = acc[mi][ni][r];
    }
  }
}

extern "C" void kernel_launch(void* const* d_in, const int* in_sizes, int n_in,
                              void* d_out, int out_size, void* d_ws, size_t ws_size,
                              hipStream_t stream) {
  const float* x  = (const float*)d_in[0];   // [4,2048,1024]
  const float* wq = (const float*)d_in[1];   // [1024,8,128]
  const float* wk = (const float*)d_in[2];
  const float* wv = (const float*)d_in[3];
  const float* wo = (const float*)d_in[4];   // [8,128,1024]
  float* out = (float*)d_out;                // [4,2048,1024] fp32

  char* ws = (char*)d_ws;
  u16* xb    = (u16*)(ws);                        // 16 MiB [8192][1024]
  u16* wqkvT = (u16*)(ws + (16u<<20));            //  6 MiB [3072][1024]
  u16* woT   = (u16*)(ws + (22u<<20));            //  2 MiB [1024][1024]
  u16* qb    = (u16*)(ws + (24u<<20));            // 16 MiB [B,H,T,D]
  u16* kb    = (u16*)(ws + (40u<<20));            // 16 MiB [B,H,T,D]
  u16* vT    = (u16*)(ws + (56u<<20));            // 16 MiB [B,H,D,T]
  u16* ob    = xb;                                // reuse xb (done after gemm_qkv)

  conv_x_k    <<<dim3(4096),  dim3(256), 0, stream>>>(x, xb);
  conv_wqkvT_k<<<dim3(12288), dim3(256), 0, stream>>>(wq, wk, wv, wqkvT);
  conv_woT_k  <<<dim3(4096),  dim3(256), 0, stream>>>(wo, woT);
  gemm_qkv_k  <<<dim3(64,24), dim3(256), 0, stream>>>(xb, wqkvT, qb, kb, vT);
  attn_k      <<<dim3(32,32), dim3(256), 0, stream>>>(qb, kb, vT, ob);
  gemm_out_k  <<<dim3(64,8),  dim3(256), 0, stream>>>(ob, woT, out);
}

// Round 2
// 280.651 us; speedup vs baseline: 1.9270x; 1.9270x over previous
//
#include <hip/hip_runtime.h>
#include <hip/hip_bf16.h>
#include <math.h>

typedef unsigned short u16;
typedef unsigned int u32;
typedef __attribute__((ext_vector_type(8))) short bf16x8;   // 8 bf16 = 4 VGPRs
typedef __attribute__((ext_vector_type(4))) float f32x4;

#define MFMA16(a,b,c) __builtin_amdgcn_mfma_f32_16x16x32_bf16(a,b,c,0,0,0)

__device__ __forceinline__ u16 f2b(float f){
  unsigned u = __float_as_uint(f);
  u += 0x7fffu + ((u >> 16) & 1u);      // RNE
  return (u16)(u >> 16);
}
__device__ __forceinline__ u32 pack2(float a, float b){
  return (u32)f2b(a) | ((u32)f2b(b) << 16);
}

// async global->LDS, 16B per lane; LDS dest = wave-uniform base + lane*16
__device__ __forceinline__ void gll16(const void* g, void* l){
  __builtin_amdgcn_global_load_lds(
      (__attribute__((address_space(1))) void*)(const_cast<void*>(g)),
      (__attribute__((address_space(3))) void*)l, 16, 0, 0);
}

// ---------------- conversions ----------------
__global__ __launch_bounds__(256) void conv_x_k(const float* __restrict__ x, u16* __restrict__ xb){
  size_t i = ((size_t)blockIdx.x*256 + threadIdx.x)*8;
  float4 a = *(const float4*)(x+i);
  float4 b = *(const float4*)(x+i+4);
  uint4 u;
  u.x = (unsigned)f2b(a.x) | ((unsigned)f2b(a.y)<<16);
  u.y = (unsigned)f2b(a.z) | ((unsigned)f2b(a.w)<<16);
  u.z = (unsigned)f2b(b.x) | ((unsigned)f2b(b.y)<<16);
  u.w = (unsigned)f2b(b.z) | ((unsigned)f2b(b.w)<<16);
  *(uint4*)(xb+i) = u;
}

// Tiled transpose-convert: dst[c][r] = bf16(src[r][c]) for 1024x1024 matrices.
// z=0..2: wq/wk/wv -> wqkvT rows z*1024.. ; z=3: wo -> woT.
__global__ __launch_bounds__(256) void conv_tr_k(
    const float* __restrict__ wq, const float* __restrict__ wk,
    const float* __restrict__ wv, const float* __restrict__ wo,
    u16* __restrict__ wqkvT, u16* __restrict__ woT)
{
  const int z = blockIdx.z;
  const float* src = (z==0)?wq:(z==1)?wk:(z==2)?wv:wo;
  u16* dst = (z<3) ? (wqkvT + (size_t)z*1024*1024) : woT;
  const int i = blockIdx.x, j = blockIdx.y;
  __shared__ u16 tile[64][72];
  const int t = threadIdx.x;
  const int cr = t >> 4, cc4 = (t & 15) * 4;
#pragma unroll
  for (int rr = 0; rr < 4; rr++){
    int r = rr*16 + cr;
    float4 v = *(const float4*)(src + (size_t)(i*64 + r)*1024 + j*64 + cc4);
    tile[cc4+0][r] = f2b(v.x);
    tile[cc4+1][r] = f2b(v.y);
    tile[cc4+2][r] = f2b(v.z);
    tile[cc4+3][r] = f2b(v.w);
  }
  __syncthreads();
  const int ro = t >> 2, co = (t & 3) * 16;
  uint4 a = *(uint4*)&tile[ro][co];
  uint4 b = *(uint4*)&tile[ro][co+8];
  u16* p = dst + (size_t)(j*64 + ro)*1024 + i*64 + co;
  *(uint4*)p = a;
  *(uint4*)(p+8) = b;
}

// ---------------- 128x128 bf16 GEMM mainloop, C = A[M][K] * B[N][K]^T ----------------
__device__ __forceinline__ void gemm128_bt(
    const u16* __restrict__ A, const u16* __restrict__ B, int K,
    int rowBase, int colBase, f32x4 acc[4][4])
{
  __shared__ __align__(16) u16 lA[128*32];
  __shared__ __align__(16) u16 lB[128*32];
  const int tid = threadIdx.x, lane = tid & 63, wave = tid >> 6;
  const int wr = wave >> 1, wc = wave & 1;
  const int qd = lane >> 4, c = lane & 15;

  int aOff[4], bOff[4];
#pragma unroll
  for (int mi=0;mi<4;mi++){ int row = wr*64 + mi*16 + c; aOff[mi] = row*32 + ((qd ^ ((row>>1)&3))*8); }
#pragma unroll
  for (int ni=0;ni<4;ni++){ int row = wc*64 + ni*16 + c; bOff[ni] = row*32 + ((qd ^ ((row>>1)&3))*8); }

  const u16* gA[2]; const u16* gB[2]; int seg[2];
#pragma unroll
  for (int c2=0;c2<2;c2++){
    int s = wave*2 + c2;
    int row = s*16 + (lane>>2);
    int gch = (lane&3) ^ ((row>>1)&3);
    gA[c2] = A + (size_t)(rowBase+row)*K + gch*8;
    gB[c2] = B + (size_t)(colBase+row)*K + gch*8;
    seg[c2] = s*512;
  }
#pragma unroll
  for (int mi=0;mi<4;mi++)
#pragma unroll
    for (int ni=0;ni<4;ni++)
#pragma unroll
      for (int e=0;e<4;e++) acc[mi][ni][e]=0.f;

  for (int k0=0; k0<K; k0+=32){
#pragma unroll
    for (int c2=0;c2<2;c2++){
      gll16(gA[c2] + k0, &lA[seg[c2]]);
      gll16(gB[c2] + k0, &lB[seg[c2]]);
    }
    __syncthreads();
    bf16x8 af[4], bb[4];
#pragma unroll
    for (int mi=0;mi<4;mi++) af[mi] = *(const bf16x8*)(lA + aOff[mi]);
#pragma unroll
    for (int ni=0;ni<4;ni++) bb[ni] = *(const bf16x8*)(lB + bOff[ni]);
#pragma unroll
    for (int ni=0;ni<4;ni++)
#pragma unroll
      for (int mi=0;mi<4;mi++)
        acc[mi][ni] = MFMA16(af[mi], bb[ni], acc[mi][ni]);
    __syncthreads();
  }
}

// ---------------- QKV GEMM + RoPE epilogue ----------------
__global__ __launch_bounds__(256) void gemm_qkv_k(
    const u16* __restrict__ xb, const u16* __restrict__ wqkvT,
    u16* __restrict__ q, u16* __restrict__ k, u16* __restrict__ vT)
{
  f32x4 acc[4][4];
  const int rowBase = blockIdx.x*128, colBase = blockIdx.y*128;
  gemm128_bt(xb, wqkvT, 1024, rowBase, colBase, acc);
  const int tid = threadIdx.x, lane = tid & 63, wave = tid >> 6;
  const int wr = wave >> 1, wc = wave & 1;
  const int qd = lane >> 4, c = lane & 15;
  const int nb = blockIdx.y;
  const int proj = nb >> 3, h = nb & 7;

  if (proj < 2){
    u16* dst = (proj==0) ? q : k;
    if (wc == 0){
      float ang0 = __powf(10000.0f, -(float)c      * (1.0f/32.0f));
      float ang1 = __powf(10000.0f, -(float)(c+16) * (1.0f/32.0f));
#pragma unroll
      for (int mi=0;mi<4;mi++){
#pragma unroll
        for (int r=0;r<4;r++){
          int row = rowBase + wr*64 + mi*16 + qd*4 + r;
          int b = row >> 11, t = row & 2047;
          long base = (((long)(b*8+h))*2048 + t)*128;
          float s0,c0,s1,c1;
          __sincosf((float)t*ang0, &s0, &c0);
          __sincosf((float)t*ang1, &s1, &c1);
          { float e = acc[mi][0][r], od = acc[mi][2][r];
            dst[base + c]      = f2b(e*c0 - od*s0);
            dst[base + c + 32] = f2b(e*s0 + od*c0); }
          { float e = acc[mi][1][r], od = acc[mi][3][r];
            dst[base + 16 + c]      = f2b(e*c1 - od*s1);
            dst[base + 16 + c + 32] = f2b(e*s1 + od*c1); }
        }
      }
    } else {
#pragma unroll
      for (int mi=0;mi<4;mi++){
#pragma unroll
        for (int r=0;r<4;r++){
          int row = rowBase + wr*64 + mi*16 + qd*4 + r;
          int b = row >> 11, t = row & 2047;
          long base = (((long)(b*8+h))*2048 + t)*128 + 64;
#pragma unroll
          for (int ni=0;ni<4;ni++)
            dst[base + ni*16 + c] = f2b(acc[mi][ni][r]);
        }
      }
    }
  } else {
#pragma unroll
    for (int mi=0;mi<4;mi++){
      int row0 = rowBase + wr*64 + mi*16 + qd*4;
      int b = row0 >> 11, t = row0 & 2047;
#pragma unroll
      for (int ni=0;ni<4;ni++){
        int d = wc*64 + ni*16 + c;
        long base = (((long)(b*8+h))*128 + d)*2048 + t;
        *(uint2*)(vT + base) = make_uint2(pack2(acc[mi][ni][0], acc[mi][ni][1]),
                                          pack2(acc[mi][ni][2], acc[mi][ni][3]));
      }
    }
  }
}

// ---------------- flash attention (S^T formulation, dbuf K/V, paired q-tiles) ----
// Block p handles q-tiles {p, 31-p}: equal work (33 kt-iters) across all 512 blocks.
// S^T = K-frag (A) x Q-frag (B): per-lane softmax over keys, only 2 shuffles.
// O^T = V^T-frag (A) x P^T-frag (B); P^T via per-wave padded LDS roundtrip.
__global__ __launch_bounds__(256, 2) void attn_k(
    const u16* __restrict__ q, const u16* __restrict__ k,
    const u16* __restrict__ vT, u16* __restrict__ o)
{
  __shared__ __align__(16) u16 lK[2][64*128];   // [t][d], chunk ^ (row&15)
  __shared__ __align__(16) u16 lV[2][64*128];   // [d][t], chunk ^ (row&7)
  __shared__ __align__(16) u16 lP[4][16*80];    // per-wave P^T->[q][key], stride 80
  const int tid = threadIdx.x, lane = tid & 63, wave = tid >> 6;
  const int qd = lane >> 4, c = lane & 15;
  const int p = blockIdx.x, bh = blockIdx.y;
  const float sc = (1.0f/128.0f) * 1.44269504088896f;

  int kOff[4][4], vOff[8][2];
#pragma unroll
  for (int ni=0;ni<4;ni++){ int row=ni*16+c;
#pragma unroll
    for (int kk=0;kk<4;kk++){ int ch=kk*4+qd; kOff[ni][kk]=row*128 + ((ch^(row&15))*8); } }
#pragma unroll
  for (int di=0;di<8;di++){ int row=di*16+c;
#pragma unroll
    for (int kk=0;kk<2;kk++){ int ch=kk*4+qd; vOff[di][kk]=row*64 + ((ch^(row&7))*8); } }

  auto loadKV = [&](int kt, int buf){
    const u16* kSrc = k + ((long)bh*2048 + kt*64)*128;
#pragma unroll
    for (int cc=0; cc<4; cc++){
      int s = wave*4+cc;
      int row = s*4 + (lane>>4);
      int gch = (lane&15) ^ (row&15);
      gll16(kSrc + (long)row*128 + gch*8, &lK[buf][s*512]);
    }
    const u16* vSrc = vT + (long)bh*128*2048 + kt*64;
#pragma unroll
    for (int cc=0; cc<4; cc++){
      int s = wave*4+cc;
      int row = s*8 + (lane>>3);
      int gch = (lane&7) ^ (row&7);
      gll16(vSrc + (long)row*2048 + gch*8, &lV[buf][s*512]);
    }
  };

  for (int sub=0; sub<2; sub++){
    const int qt = sub ? (31 - p) : p;
    const int q0 = qt * 64;

    bf16x8 aQ[4];
    {
      const long qrow = (long)bh*2048 + q0 + wave*16 + c;
#pragma unroll
      for (int kk=0;kk<4;kk++)
        aQ[kk] = *(const bf16x8*)(q + qrow*128 + kk*32 + qd*8);
    }
    f32x4 accO[8];
#pragma unroll
    for (int i=0;i<8;i++)
#pragma unroll
      for (int e=0;e<4;e++) accO[i][e]=0.f;
    float m2v = -INFINITY, lv = 0.f;

    __syncthreads();            // prior sub's LDS readers done
    loadKV(0, 0);
    int cur = 0;

    for (int kt=0; kt<=qt; kt++){
      __syncthreads();          // drains vmcnt(0): buf[cur] ready; buf[cur^1] readers done
      if (kt < qt) loadKV(kt+1, cur^1);

      // S^T tile: D[key][q]
      f32x4 accS[4];
#pragma unroll
      for (int ni=0;ni<4;ni++)
#pragma unroll
        for (int e=0;e<4;e++) accS[ni][e]=0.f;
#pragma unroll
      for (int kk=0;kk<4;kk++)
#pragma unroll
        for (int ni=0;ni<4;ni++){
          bf16x8 ak = *(const bf16x8*)(&lK[cur][kOff[ni][kk]]);
          accS[ni] = MFMA16(ak, aQ[kk], accS[ni]);
        }

      if (kt == qt){
        const int lim = wave*16 + c;      // local q index within the 64-row tile
#pragma unroll
        for (int ni=0;ni<4;ni++)
#pragma unroll
          for (int r=0;r<4;r++)
            if (ni*16 + qd*4 + r > lim) accS[ni][r] = -INFINITY;
      }

      // per-lane softmax over 16 key-entries + 2 shuffles across quads
      float vmax = -3.4e38f;
#pragma unroll
      for (int ni=0;ni<4;ni++)
#pragma unroll
        for (int r=0;r<4;r++) vmax = fmaxf(vmax, accS[ni][r]);
      vmax *= sc;
      vmax = fmaxf(vmax, __shfl_xor(vmax, 16));
      vmax = fmaxf(vmax, __shfl_xor(vmax, 32));
      float mNew = fmaxf(m2v, vmax);
      float alpha = exp2f(m2v - mNew);
      m2v = mNew;

      float pv[4][4]; float ps = 0.f;
#pragma unroll
      for (int ni=0;ni<4;ni++)
#pragma unroll
        for (int r=0;r<4;r++){
          float pe = exp2f(accS[ni][r]*sc - mNew);
          pv[ni][r] = pe; ps += pe;
        }
      ps += __shfl_xor(ps, 16);
      ps += __shfl_xor(ps, 32);
      lv = lv*alpha + ps;

      // P^T -> per-wave LDS [q][key], stride 80 u16 (16B-aligned reads)
      {
        u32* lw = (u32*)&lP[wave][0];
#pragma unroll
        for (int ni=0;ni<4;ni++)
#pragma unroll
          for (int pr=0;pr<2;pr++)
            lw[c*40 + ni*8 + qd*2 + pr] = pack2(pv[ni][2*pr], pv[ni][2*pr+1]);
      }
#pragma unroll
      for (int di=0;di<8;di++)
#pragma unroll
        for (int e=0;e<4;e++) accO[di][e] *= alpha;

#pragma unroll
      for (int kk=0;kk<2;kk++){
        bf16x8 bp = *(const bf16x8*)(&lP[wave][c*80 + kk*32 + qd*8]);
#pragma unroll
        for (int di=0;di<8;di++){
          bf16x8 av = *(const bf16x8*)(&lV[cur][vOff[di][kk]]);
          accO[di] = MFMA16(av, bp, accO[di]);
        }
      }
      cur ^= 1;
    }

    // epilogue: lane holds O^T[d=di*16+qd*4+r][q=c]
    const int b = bh >> 3, h = bh & 7;
    const float inv = 1.0f / lv;
    const long base = ((long)(b*2048 + q0 + wave*16 + c))*1024 + h*128;
#pragma unroll
    for (int di=0;di<8;di++){
      *(uint2*)(o + base + di*16 + qd*4) =
        make_uint2(pack2(accO[di][0]*inv, accO[di][1]*inv),
                   pack2(accO[di][2]*inv, accO[di][3]*inv));
    }
  }
}

// ---------------- output projection ----------------
__global__ __launch_bounds__(256) void gemm_out_k(
    const u16* __restrict__ oa, const u16* __restrict__ woT, float* __restrict__ out)
{
  f32x4 acc[4][4];
  const int rowBase = blockIdx.x*128, colBase = blockIdx.y*128;
  gemm128_bt(oa, woT, 1024, rowBase, colBase, acc);
  const int lane = threadIdx.x & 63, wave = threadIdx.x >> 6;
  const int wr = wave >> 1, wc = wave & 1;
  const int qd = lane >> 4, c = lane & 15;
#pragma unroll
  for (int mi=0;mi<4;mi++){
#pragma unroll
    for (int ni=0;ni<4;ni++){
      int row = rowBase + wr*64 + mi*16 + qd*4;
      int col = colBase + wc*64 + ni*16 + c;
#pragma unroll
      for (int r=0;r<4;r++)
        out[(size_t)(row+r)*1024 + col] = acc[mi][ni][r];
    }
  }
}

extern "C" void kernel_launch(void* const* d_in, const int* in_sizes, int n_in,
                              void* d_out, int out_size, void* d_ws, size_t ws_size,
                              hipStream_t stream) {
  const float* x  = (const float*)d_in[0];
  const float* wq = (const float*)d_in[1];
  const float* wk = (const float*)d_in[2];
  const float* wv = (const float*)d_in[3];
  const float* wo = (const float*)d_in[4];
  float* out = (float*)d_out;

  char* ws = (char*)d_ws;
  u16* xb    = (u16*)(ws);
  u16* wqkvT = (u16*)(ws + (16u<<20));
  u16* woT   = (u16*)(ws + (22u<<20));
  u16* qb    = (u16*)(ws + (24u<<20));
  u16* kb    = (u16*)(ws + (40u<<20));
  u16* vT    = (u16*)(ws + (56u<<20));
  u16* ob    = xb;   // reuse xb after gemm_qkv

  conv_x_k  <<<dim3(4096), dim3(256), 0, stream>>>(x, xb);
  conv_tr_k <<<dim3(16,16,4), dim3(256), 0, stream>>>(wq, wk, wv, wo, wqkvT, woT);
  gemm_qkv_k<<<dim3(64,24), dim3(256), 0, stream>>>(xb, wqkvT, qb, kb, vT);
  attn_k    <<<dim3(16,32), dim3(256), 0, stream>>>(qb, kb, vT, ob);
  gemm_out_k<<<dim3(64,8),  dim3(256), 0, stream>>>(ob, woT, out);
}

// Round 3
// 263.723 us; speedup vs baseline: 2.0507x; 1.0642x over previous
//
#include <hip/hip_runtime.h>
#include <hip/hip_bf16.h>
#include <math.h>

typedef unsigned short u16;
typedef unsigned int u32;
typedef __attribute__((ext_vector_type(8))) short bf16x8;   // 8 bf16 = 4 VGPRs
typedef __attribute__((ext_vector_type(4))) float f32x4;
typedef __attribute__((ext_vector_type(16))) float f32x16;

#define MFMA16(a,b,c) __builtin_amdgcn_mfma_f32_16x16x32_bf16(a,b,c,0,0,0)
#define MFMA32(a,b,c) __builtin_amdgcn_mfma_f32_32x32x16_bf16(a,b,c,0,0,0)

__device__ __forceinline__ u16 f2b(float f){
  unsigned u = __float_as_uint(f);
  u += 0x7fffu + ((u >> 16) & 1u);      // RNE
  return (u16)(u >> 16);
}
__device__ __forceinline__ u32 pack2(float a, float b){
  return (u32)f2b(a) | ((u32)f2b(b) << 16);
}

// async global->LDS, 16B per lane; LDS dest = wave-uniform base + lane*16
__device__ __forceinline__ void gll16(const void* g, void* l){
  __builtin_amdgcn_global_load_lds(
      (__attribute__((address_space(1))) void*)(const_cast<void*>(g)),
      (__attribute__((address_space(3))) void*)l, 16, 0, 0);
}

// ---------------- conversions ----------------
__global__ __launch_bounds__(256) void conv_x_k(const float* __restrict__ x, u16* __restrict__ xb){
  size_t i = ((size_t)blockIdx.x*256 + threadIdx.x)*8;
  float4 a = *(const float4*)(x+i);
  float4 b = *(const float4*)(x+i+4);
  uint4 u;
  u.x = (unsigned)f2b(a.x) | ((unsigned)f2b(a.y)<<16);
  u.y = (unsigned)f2b(a.z) | ((unsigned)f2b(a.w)<<16);
  u.z = (unsigned)f2b(b.x) | ((unsigned)f2b(b.y)<<16);
  u.w = (unsigned)f2b(b.z) | ((unsigned)f2b(b.w)<<16);
  *(uint4*)(xb+i) = u;
}

// Tiled transpose-convert: dst[c][r] = bf16(src[r][c]) for 1024x1024 matrices.
__global__ __launch_bounds__(256) void conv_tr_k(
    const float* __restrict__ wq, const float* __restrict__ wk,
    const float* __restrict__ wv, const float* __restrict__ wo,
    u16* __restrict__ wqkvT, u16* __restrict__ woT)
{
  const int z = blockIdx.z;
  const float* src = (z==0)?wq:(z==1)?wk:(z==2)?wv:wo;
  u16* dst = (z<3) ? (wqkvT + (size_t)z*1024*1024) : woT;
  const int i = blockIdx.x, j = blockIdx.y;
  __shared__ u16 tile[64][72];
  const int t = threadIdx.x;
  const int cr = t >> 4, cc4 = (t & 15) * 4;
#pragma unroll
  for (int rr = 0; rr < 4; rr++){
    int r = rr*16 + cr;
    float4 v = *(const float4*)(src + (size_t)(i*64 + r)*1024 + j*64 + cc4);
    tile[cc4+0][r] = f2b(v.x);
    tile[cc4+1][r] = f2b(v.y);
    tile[cc4+2][r] = f2b(v.z);
    tile[cc4+3][r] = f2b(v.w);
  }
  __syncthreads();
  const int ro = t >> 2, co = (t & 3) * 16;
  uint4 a = *(uint4*)&tile[ro][co];
  uint4 b = *(uint4*)&tile[ro][co+8];
  u16* p = dst + (size_t)(j*64 + ro)*1024 + i*64 + co;
  *(uint4*)p = a;
  *(uint4*)(p+8) = b;
}

// ---------------- 128x128 bf16 GEMM mainloop, C = A[M][K] * B[N][K]^T ----------------
__device__ __forceinline__ void gemm128_bt(
    const u16* __restrict__ A, const u16* __restrict__ B, int K,
    int rowBase, int colBase, f32x4 acc[4][4])
{
  __shared__ __align__(16) u16 lA[128*32];
  __shared__ __align__(16) u16 lB[128*32];
  const int tid = threadIdx.x, lane = tid & 63, wave = tid >> 6;
  const int wr = wave >> 1, wc = wave & 1;
  const int qd = lane >> 4, c = lane & 15;

  int aOff[4], bOff[4];
#pragma unroll
  for (int mi=0;mi<4;mi++){ int row = wr*64 + mi*16 + c; aOff[mi] = row*32 + ((qd ^ ((row>>1)&3))*8); }
#pragma unroll
  for (int ni=0;ni<4;ni++){ int row = wc*64 + ni*16 + c; bOff[ni] = row*32 + ((qd ^ ((row>>1)&3))*8); }

  const u16* gA[2]; const u16* gB[2]; int seg[2];
#pragma unroll
  for (int c2=0;c2<2;c2++){
    int s = wave*2 + c2;
    int row = s*16 + (lane>>2);
    int gch = (lane&3) ^ ((row>>1)&3);
    gA[c2] = A + (size_t)(rowBase+row)*K + gch*8;
    gB[c2] = B + (size_t)(colBase+row)*K + gch*8;
    seg[c2] = s*512;
  }
#pragma unroll
  for (int mi=0;mi<4;mi++)
#pragma unroll
    for (int ni=0;ni<4;ni++)
#pragma unroll
      for (int e=0;e<4;e++) acc[mi][ni][e]=0.f;

  for (int k0=0; k0<K; k0+=32){
#pragma unroll
    for (int c2=0;c2<2;c2++){
      gll16(gA[c2] + k0, &lA[seg[c2]]);
      gll16(gB[c2] + k0, &lB[seg[c2]]);
    }
    __syncthreads();
    bf16x8 af[4], bb[4];
#pragma unroll
    for (int mi=0;mi<4;mi++) af[mi] = *(const bf16x8*)(lA + aOff[mi]);
#pragma unroll
    for (int ni=0;ni<4;ni++) bb[ni] = *(const bf16x8*)(lB + bOff[ni]);
#pragma unroll
    for (int ni=0;ni<4;ni++)
#pragma unroll
      for (int mi=0;mi<4;mi++)
        acc[mi][ni] = MFMA16(af[mi], bb[ni], acc[mi][ni]);
    __syncthreads();
  }
}

// ---------------- QKV GEMM + RoPE epilogue ----------------
// q is pre-scaled by QSC = log2(e)/128 so attention can use exp2 with no extra muls.
#define QSC (1.44269504088896f/128.0f)
__global__ __launch_bounds__(256) void gemm_qkv_k(
    const u16* __restrict__ xb, const u16* __restrict__ wqkvT,
    u16* __restrict__ q, u16* __restrict__ k, u16* __restrict__ vT)
{
  f32x4 acc[4][4];
  const int rowBase = blockIdx.x*128, colBase = blockIdx.y*128;
  gemm128_bt(xb, wqkvT, 1024, rowBase, colBase, acc);
  const int tid = threadIdx.x, lane = tid & 63, wave = tid >> 6;
  const int wr = wave >> 1, wc = wave & 1;
  const int qd = lane >> 4, c = lane & 15;
  const int nb = blockIdx.y;
  const int proj = nb >> 3, h = nb & 7;

  if (proj < 2){
    u16* dst = (proj==0) ? q : k;
    const float os = (proj==0) ? QSC : 1.0f;
    if (wc == 0){
      float ang0 = __powf(10000.0f, -(float)c      * (1.0f/32.0f));
      float ang1 = __powf(10000.0f, -(float)(c+16) * (1.0f/32.0f));
#pragma unroll
      for (int mi=0;mi<4;mi++){
#pragma unroll
        for (int r=0;r<4;r++){
          int row = rowBase + wr*64 + mi*16 + qd*4 + r;
          int b = row >> 11, t = row & 2047;
          long base = (((long)(b*8+h))*2048 + t)*128;
          float s0,c0,s1,c1;
          __sincosf((float)t*ang0, &s0, &c0);
          __sincosf((float)t*ang1, &s1, &c1);
          { float e = acc[mi][0][r], od = acc[mi][2][r];
            dst[base + c]      = f2b((e*c0 - od*s0)*os);
            dst[base + c + 32] = f2b((e*s0 + od*c0)*os); }
          { float e = acc[mi][1][r], od = acc[mi][3][r];
            dst[base + 16 + c]      = f2b((e*c1 - od*s1)*os);
            dst[base + 16 + c + 32] = f2b((e*s1 + od*c1)*os); }
        }
      }
    } else {
#pragma unroll
      for (int mi=0;mi<4;mi++){
#pragma unroll
        for (int r=0;r<4;r++){
          int row = rowBase + wr*64 + mi*16 + qd*4 + r;
          int b = row >> 11, t = row & 2047;
          long base = (((long)(b*8+h))*2048 + t)*128 + 64;
#pragma unroll
          for (int ni=0;ni<4;ni++)
            dst[base + ni*16 + c] = f2b(acc[mi][ni][r]*os);
        }
      }
    }
  } else {
#pragma unroll
    for (int mi=0;mi<4;mi++){
      int row0 = rowBase + wr*64 + mi*16 + qd*4;
      int b = row0 >> 11, t = row0 & 2047;
#pragma unroll
      for (int ni=0;ni<4;ni++){
        int d = wc*64 + ni*16 + c;
        long base = (((long)(b*8+h))*128 + d)*2048 + t;
        *(uint2*)(vT + base) = make_uint2(pack2(acc[mi][ni][0], acc[mi][ni][1]),
                                          pack2(acc[mi][ni][2], acc[mi][ni][3]));
      }
    }
  }
}

// ---------------- flash attention v3 ----------------
// 512 threads, q-tile 128, K-tile 64. Wave (qs,kh): q-strip qs*32, key-half kh*32.
// 32x32x16 MFMA. Fixed-max softmax: P = exp2(S*log2e/128) (scale folded into q),
// l deferred to per-lane register; cross-kh combine once per sub via LDS.
// Block pairing {p, 15-p}: every block runs exactly 34 kt-iterations.
__global__ __launch_bounds__(512, 2) void attn_k(
    const u16* __restrict__ q, const u16* __restrict__ k,
    const u16* __restrict__ vT, u16* __restrict__ o)
{
  __shared__ __align__(16) u16 smem[40960];        // 80 KB
  u16* lK = smem;                                  // [2][64 key][128 d], swiz ^(row&15)
  u16* lV = smem + 16384;                          // [2][128 d][64 key], swiz ^(row&7)
  u16* lP = smem + 32768;                          // [4 qs][32 q][64 key], swiz ^(q&7)
  float* scrO = (float*)smem;                      // epilogue [16][32][32]
  float* scrL = (float*)(smem + 32768);            // epilogue [2][128]

  const int tid = threadIdx.x, lane = tid & 63, wave = tid >> 6;
  const int h2 = lane >> 5, ln = lane & 31;
  const int qs = wave >> 1, kh = wave & 1;
  const int bh = blockIdx.x, p = blockIdx.y;

  auto loadKV = [&](int kt, int buf){
    const u16* kSrc = k + ((long)bh*2048 + kt*64)*128;
#pragma unroll
    for (int cc=0; cc<2; cc++){
      int s = wave*2+cc;
      int row = s*4 + (lane>>4);
      int gch = (lane&15) ^ (row&15);
      gll16(kSrc + row*128 + gch*8, lK + buf*8192 + s*512);
    }
    const u16* vSrc = vT + (long)bh*128*2048 + kt*64;
#pragma unroll
    for (int cc=0; cc<2; cc++){
      int s = wave*2+cc;
      int row = s*8 + (lane>>3);
      int gch = (lane&7) ^ (row&7);
      gll16(vSrc + (long)row*2048 + gch*8, lV + buf*8192 + s*512);
    }
  };

  for (int sub=0; sub<2; sub++){
    const int qt = sub ? (15 - p) : p;
    const int q0 = qt*128;
    const int qw = q0 + qs*32;          // wave's q-strip base

    bf16x8 aQ[8];
    {
      const long qrow = (long)bh*2048 + qw + ln;
#pragma unroll
      for (int ch=0; ch<8; ch++)
        aQ[ch] = *(const bf16x8*)(q + qrow*128 + ch*16 + h2*8);
    }
    f32x16 accO[4];
#pragma unroll
    for (int dt=0; dt<4; dt++)
#pragma unroll
      for (int r=0;r<16;r++) accO[dt][r] = 0.f;
    float lsum = 0.f;

    __syncthreads();                    // prior sub's LDS users done
    loadKV(0, 0);
    int cur = 0;
    const int ktMax = 2*qt + 1;

    for (int kt=0; kt<=ktMax; kt++){
      __syncthreads();                  // buf[cur] ready; buf[cur^1] readers done
      if (kt < ktMax) loadKV(kt+1, cur^1);

      const int key0 = kt*64 + kh*32;
      if (key0 <= qw + 31){             // not fully masked for this wave
        // S^T[key][q] 32x32: A = K-half, B = Q-strip
        f32x16 accS;
#pragma unroll
        for (int r=0;r<16;r++) accS[r] = 0.f;
        const int krow = kh*32 + ln;
#pragma unroll
        for (int ch=0; ch<8; ch++){
          bf16x8 ak = *(const bf16x8*)(lK + cur*8192 + krow*128 + (((ch*2+h2) ^ (krow&15))*8));
          accS = MFMA32(ak, aQ[ch], accS);
        }

        const bool diag = (key0 + 31 > qw);
        float pe[16];
        float ls0 = 0.f, ls1 = 0.f;
#pragma unroll
        for (int r=0;r<16;r++){
          float s = accS[r];
          if (diag){
            int keyg = key0 + (r&3) + 8*(r>>2) + 4*h2;
            if (keyg > qw + ln) s = -INFINITY;   // exp2(-inf) = 0
          }
          pe[r] = exp2f(s);
          if (r & 1) ls1 += pe[r]; else ls0 += pe[r];
        }
        lsum += ls0 + ls1;

        // P -> lP [q][key], b64 per reg-quad (keys contiguous)
        {
          u16* lpw = lP + qs*2048 + ln*64;
#pragma unroll
          for (int g=0; g<4; g++){
            uint2 w = make_uint2(pack2(pe[4*g], pe[4*g+1]), pack2(pe[4*g+2], pe[4*g+3]));
            *(uint2*)(lpw + (((kh*4+g) ^ (ln&7))*8) + h2*4) = w;
          }
        }

        // O[q][d] partial: A = P (own strip, own key-half), B = V^T
#pragma unroll
        for (int kk=0; kk<2; kk++){
          bf16x8 ap = *(const bf16x8*)(lP + qs*2048 + ln*64 + (((kh*4+kk*2+h2) ^ (ln&7))*8));
#pragma unroll
          for (int dt=0; dt<4; dt++){
            int vrow = dt*32 + ln;
            bf16x8 bv = *(const bf16x8*)(lV + cur*8192 + vrow*64 + (((kh*4+kk*2+h2) ^ (vrow&7))*8));
            accO[dt] = MFMA32(ap, bv, accO[dt]);
          }
        }
      }
      cur ^= 1;
    }

    // ---- epilogue: combine kh halves, normalize, store ----
    lsum += __shfl_xor(lsum, 32);       // fold h2 halves: all lanes hold their q's half-sum
    __syncthreads();                    // main-loop LDS reads done before alias reuse
    if (kh == 1){
#pragma unroll
      for (int dt=0; dt<4; dt++)
#pragma unroll
        for (int r=0;r<16;r++){
          int row = (r&3) + 8*(r>>2) + 4*h2;
          scrO[((qs*4+dt)*32 + row)*32 + ln] = accO[dt][r];
        }
      if (h2 == 0) scrL[128 + qs*32 + ln] = lsum;
    } else {
      if (h2 == 0) scrL[qs*32 + ln] = lsum;
    }
    __syncthreads();
    if (kh == 0){
      float linv[16];
#pragma unroll
      for (int r=0;r<16;r++){
        int row = (r&3) + 8*(r>>2) + 4*h2;
        linv[r] = 1.0f / (scrL[qs*32 + row] + scrL[128 + qs*32 + row]);
      }
      const int b = bh >> 3, h = bh & 7;
#pragma unroll
      for (int dt=0; dt<4; dt++){
#pragma unroll
        for (int r=0;r<16;r++){
          int row = (r&3) + 8*(r>>2) + 4*h2;
          float val = accO[dt][r] + scrO[((qs*4+dt)*32 + row)*32 + ln];
          int t = q0 + qs*32 + row;
          o[((long)(b*2048 + t))*1024 + h*128 + dt*32 + ln] = f2b(val * linv[r]);
        }
      }
    }
  }
}

// ---------------- output projection ----------------
__global__ __launch_bounds__(256) void gemm_out_k(
    const u16* __restrict__ oa, const u16* __restrict__ woT, float* __restrict__ out)
{
  f32x4 acc[4][4];
  const int rowBase = blockIdx.x*128, colBase = blockIdx.y*128;
  gemm128_bt(oa, woT, 1024, rowBase, colBase, acc);
  const int lane = threadIdx.x & 63, wave = threadIdx.x >> 6;
  const int wr = wave >> 1, wc = wave & 1;
  const int qd = lane >> 4, c = lane & 15;
#pragma unroll
  for (int mi=0;mi<4;mi++){
#pragma unroll
    for (int ni=0;ni<4;ni++){
      int row = rowBase + wr*64 + mi*16 + qd*4;
      int col = colBase + wc*64 + ni*16 + c;
#pragma unroll
      for (int r=0;r<4;r++)
        out[(size_t)(row+r)*1024 + col] = acc[mi][ni][r];
    }
  }
}

extern "C" void kernel_launch(void* const* d_in, const int* in_sizes, int n_in,
                              void* d_out, int out_size, void* d_ws, size_t ws_size,
                              hipStream_t stream) {
  const float* x  = (const float*)d_in[0];
  const float* wq = (const float*)d_in[1];
  const float* wk = (const float*)d_in[2];
  const float* wv = (const float*)d_in[3];
  const float* wo = (const float*)d_in[4];
  float* out = (float*)d_out;

  char* ws = (char*)d_ws;
  u16* xb    = (u16*)(ws);
  u16* wqkvT = (u16*)(ws + (16u<<20));
  u16* woT   = (u16*)(ws + (22u<<20));
  u16* qb    = (u16*)(ws + (24u<<20));
  u16* kb    = (u16*)(ws + (40u<<20));
  u16* vT    = (u16*)(ws + (56u<<20));
  u16* ob    = xb;   // reuse xb after gemm_qkv

  conv_x_k  <<<dim3(4096), dim3(256), 0, stream>>>(x, xb);
  conv_tr_k <<<dim3(16,16,4), dim3(256), 0, stream>>>(wq, wk, wv, wo, wqkvT, woT);
  gemm_qkv_k<<<dim3(64,24), dim3(256), 0, stream>>>(xb, wqkvT, qb, kb, vT);
  attn_k    <<<dim3(32,8), dim3(512), 0, stream>>>(qb, kb, vT, ob);
  gemm_out_k<<<dim3(64,8),  dim3(256), 0, stream>>>(ob, woT, out);
}

// Round 4
// 251.920 us; speedup vs baseline: 2.1468x; 1.0469x over previous
//
#include <hip/hip_runtime.h>
#include <hip/hip_bf16.h>
#include <math.h>

typedef unsigned short u16;
typedef unsigned int u32;
typedef __attribute__((ext_vector_type(8))) short bf16x8;   // 8 bf16 = 4 VGPRs
typedef __attribute__((ext_vector_type(4))) float f32x4;
typedef __attribute__((ext_vector_type(16))) float f32x16;

#define MFMA16(a,b,c) __builtin_amdgcn_mfma_f32_16x16x32_bf16(a,b,c,0,0,0)
#define MFMA32(a,b,c) __builtin_amdgcn_mfma_f32_32x32x16_bf16(a,b,c,0,0,0)

__device__ __forceinline__ u16 f2b(float f){
  unsigned u = __float_as_uint(f);
  u += 0x7fffu + ((u >> 16) & 1u);      // RNE
  return (u16)(u >> 16);
}
__device__ __forceinline__ u32 pack2(float a, float b){
  return (u32)f2b(a) | ((u32)f2b(b) << 16);
}

// async global->LDS, 16B per lane; LDS dest = wave-uniform base + lane*16
__device__ __forceinline__ void gll16(const void* g, void* l){
  __builtin_amdgcn_global_load_lds(
      (__attribute__((address_space(1))) void*)(const_cast<void*>(g)),
      (__attribute__((address_space(3))) void*)l, 16, 0, 0);
}

// ---------------- merged conversions ----------------
// blocks [0,4096): x -> bf16.  blocks [4096,5120): transpose-convert weights.
__global__ __launch_bounds__(256) void conv_k(
    const float* __restrict__ x,  const float* __restrict__ wq,
    const float* __restrict__ wk, const float* __restrict__ wv,
    const float* __restrict__ wo, u16* __restrict__ xb,
    u16* __restrict__ wqkvT, u16* __restrict__ woT)
{
  const int bid = blockIdx.x;
  if (bid < 4096){
    size_t i = ((size_t)bid*256 + threadIdx.x)*8;
    float4 a = *(const float4*)(x+i);
    float4 b = *(const float4*)(x+i+4);
    uint4 u;
    u.x = pack2(a.x, a.y);
    u.y = pack2(a.z, a.w);
    u.z = pack2(b.x, b.y);
    u.w = pack2(b.z, b.w);
    *(uint4*)(xb+i) = u;
    return;
  }
  const int id = bid - 4096;            // 0..1023
  const int z = id >> 8, rem = id & 255, i = rem >> 4, j = rem & 15;
  const float* src = (z==0)?wq:(z==1)?wk:(z==2)?wv:wo;
  u16* dst = (z<3) ? (wqkvT + (size_t)z*1024*1024) : woT;
  __shared__ u16 tile[64][72];
  const int t = threadIdx.x;
  const int cr = t >> 4, cc4 = (t & 15) * 4;
#pragma unroll
  for (int rr = 0; rr < 4; rr++){
    int r = rr*16 + cr;
    float4 v = *(const float4*)(src + (size_t)(i*64 + r)*1024 + j*64 + cc4);
    tile[cc4+0][r] = f2b(v.x);
    tile[cc4+1][r] = f2b(v.y);
    tile[cc4+2][r] = f2b(v.z);
    tile[cc4+3][r] = f2b(v.w);
  }
  __syncthreads();
  const int ro = t >> 2, co = (t & 3) * 16;
  uint4 a = *(uint4*)&tile[ro][co];
  uint4 b = *(uint4*)&tile[ro][co+8];
  u16* p = dst + (size_t)(j*64 + ro)*1024 + i*64 + co;
  *(uint4*)p = a;
  *(uint4*)(p+8) = b;
}

// ---------------- 128x128 bf16 GEMM mainloop, BK=64, C = A[M][K] * B[N][K]^T ------
// LDS row = 64 u16 (8 chunks of 8); chunk slot = ch ^ (row&7). 16 iters at K=1024.
__device__ __forceinline__ void gemm128_bt(
    const u16* __restrict__ A, const u16* __restrict__ B, int K,
    int rowBase, int colBase, f32x4 acc[4][4])
{
  __shared__ __align__(16) u16 lA[128*64];
  __shared__ __align__(16) u16 lB[128*64];
  const int tid = threadIdx.x, lane = tid & 63, wave = tid >> 6;
  const int wr = wave >> 1, wc = wave & 1;
  const int qd = lane >> 4, c = lane & 15;

  int aOff[4], bOff[4];                 // kb=1 offset = kb0 ^ 32
#pragma unroll
  for (int mi=0;mi<4;mi++){ int row = wr*64 + mi*16 + c; aOff[mi] = row*64 + ((qd ^ (row&7))*8); }
#pragma unroll
  for (int ni=0;ni<4;ni++){ int row = wc*64 + ni*16 + c; bOff[ni] = row*64 + ((qd ^ (row&7))*8); }

  const u16* gA[4]; const u16* gB[4]; int seg[4];
#pragma unroll
  for (int cc=0;cc<4;cc++){
    int s = wave*4 + cc;
    int row = s*8 + (lane>>3);
    int gch = (lane&7) ^ (row&7);
    gA[cc] = A + (size_t)(rowBase+row)*K + gch*8;
    gB[cc] = B + (size_t)(colBase+row)*K + gch*8;
    seg[cc] = s*512;
  }
#pragma unroll
  for (int mi=0;mi<4;mi++)
#pragma unroll
    for (int ni=0;ni<4;ni++)
#pragma unroll
      for (int e=0;e<4;e++) acc[mi][ni][e]=0.f;

  for (int k0=0; k0<K; k0+=64){
#pragma unroll
    for (int cc=0;cc<4;cc++){
      gll16(gA[cc] + k0, &lA[seg[cc]]);
      gll16(gB[cc] + k0, &lB[seg[cc]]);
    }
    __syncthreads();
#pragma unroll
    for (int kb=0; kb<2; kb++){
      const int x = kb*32;
      bf16x8 af[4], bb[4];
#pragma unroll
      for (int mi=0;mi<4;mi++) af[mi] = *(const bf16x8*)(lA + (aOff[mi]^x));
#pragma unroll
      for (int ni=0;ni<4;ni++) bb[ni] = *(const bf16x8*)(lB + (bOff[ni]^x));
#pragma unroll
      for (int ni=0;ni<4;ni++)
#pragma unroll
        for (int mi=0;mi<4;mi++)
          acc[mi][ni] = MFMA16(af[mi], bb[ni], acc[mi][ni]);
    }
    __syncthreads();
  }
}

// ---------------- QKV GEMM + RoPE epilogue ----------------
// q pre-scaled by QSC = log2(e)/128 so attention uses exp2 directly.
// RoPE'd dims stored INTERLEAVED: d' = 2j   -> rotated-even of pair j,
//                                 d' = 2j+1 -> rotated-odd  of pair j  (j in [0,32)).
// d' in [64,128) = pass-through. Same permutation for q and k => dot products exact.
#define QSC (1.44269504088896f/128.0f)
__global__ __launch_bounds__(256) void gemm_qkv_k(
    const u16* __restrict__ xb, const u16* __restrict__ wqkvT,
    u16* __restrict__ q, u16* __restrict__ k, u16* __restrict__ vT)
{
  f32x4 acc[4][4];
  const int rowBase = blockIdx.x*128, colBase = blockIdx.y*128;
  gemm128_bt(xb, wqkvT, 1024, rowBase, colBase, acc);
  const int tid = threadIdx.x, lane = tid & 63, wave = tid >> 6;
  const int wr = wave >> 1, wc = wave & 1;
  const int qd = lane >> 4, c = lane & 15;
  const int nb = blockIdx.y;
  const int proj = nb >> 3, h = nb & 7;

  if (proj < 2){
    u16* dst = (proj==0) ? q : k;
    const float os = (proj==0) ? QSC : 1.0f;
    if (wc == 0){
      // pairs j=c (tiles 0,2) and j=c+16 (tiles 1,3)
      float ang0 = __powf(10000.0f, -(float)c      * (1.0f/32.0f));
      float ang1 = __powf(10000.0f, -(float)(c+16) * (1.0f/32.0f));
#pragma unroll
      for (int mi=0;mi<4;mi++){
#pragma unroll
        for (int r=0;r<4;r++){
          int row = rowBase + wr*64 + mi*16 + qd*4 + r;
          int b = row >> 11, t = row & 2047;
          u32* dst32 = (u32*)(dst + (((long)(b*8+h))*2048 + t)*128);
          float s0,c0,s1,c1;
          __sincosf((float)t*ang0, &s0, &c0);
          __sincosf((float)t*ang1, &s1, &c1);
          { float e = acc[mi][0][r], od = acc[mi][2][r];
            dst32[c]      = pack2((e*c0 - od*s0)*os, (e*s0 + od*c0)*os); }
          { float e = acc[mi][1][r], od = acc[mi][3][r];
            dst32[16 + c] = pack2((e*c1 - od*s1)*os, (e*s1 + od*c1)*os); }
        }
      }
    } else {
      // pass-through half d in [64,128)
#pragma unroll
      for (int mi=0;mi<4;mi++){
#pragma unroll
        for (int r=0;r<4;r++){
          int row = rowBase + wr*64 + mi*16 + qd*4 + r;
          int b = row >> 11, t = row & 2047;
          long base = (((long)(b*8+h))*2048 + t)*128 + 64;
#pragma unroll
          for (int ni=0;ni<4;ni++)
            dst[base + ni*16 + c] = f2b(acc[mi][ni][r]*os);
        }
      }
    }
  } else {
#pragma unroll
    for (int mi=0;mi<4;mi++){
      int row0 = rowBase + wr*64 + mi*16 + qd*4;
      int b = row0 >> 11, t = row0 & 2047;
#pragma unroll
      for (int ni=0;ni<4;ni++){
        int d = wc*64 + ni*16 + c;
        long base = (((long)(b*8+h))*128 + d)*2048 + t;
        *(uint2*)(vT + base) = make_uint2(pack2(acc[mi][ni][0], acc[mi][ni][1]),
                                          pack2(acc[mi][ni][2], acc[mi][ni][3]));
      }
    }
  }
}

// ---------------- flash attention (layout-agnostic over d) ----------------
__global__ __launch_bounds__(512, 2) void attn_k(
    const u16* __restrict__ q, const u16* __restrict__ k,
    const u16* __restrict__ vT, u16* __restrict__ o)
{
  __shared__ __align__(16) u16 smem[40960];        // 80 KB
  u16* lK = smem;                                  // [2][64 key][128 d], swiz ^(row&15)
  u16* lV = smem + 16384;                          // [2][128 d][64 key], swiz ^(row&7)
  u16* lP = smem + 32768;                          // [4 qs][32 q][64 key], swiz ^(q&7)
  float* scrO = (float*)smem;                      // epilogue [16][32][32]
  float* scrL = (float*)(smem + 32768);            // epilogue [2][128]

  const int tid = threadIdx.x, lane = tid & 63, wave = tid >> 6;
  const int h2 = lane >> 5, ln = lane & 31;
  const int qs = wave >> 1, kh = wave & 1;
  const int bh = blockIdx.x, p = blockIdx.y;

  auto loadKV = [&](int kt, int buf){
    const u16* kSrc = k + ((long)bh*2048 + kt*64)*128;
#pragma unroll
    for (int cc=0; cc<2; cc++){
      int s = wave*2+cc;
      int row = s*4 + (lane>>4);
      int gch = (lane&15) ^ (row&15);
      gll16(kSrc + row*128 + gch*8, lK + buf*8192 + s*512);
    }
    const u16* vSrc = vT + (long)bh*128*2048 + kt*64;
#pragma unroll
    for (int cc=0; cc<2; cc++){
      int s = wave*2+cc;
      int row = s*8 + (lane>>3);
      int gch = (lane&7) ^ (row&7);
      gll16(vSrc + (long)row*2048 + gch*8, lV + buf*8192 + s*512);
    }
  };

  for (int sub=0; sub<2; sub++){
    const int qt = sub ? (15 - p) : p;
    const int q0 = qt*128;
    const int qw = q0 + qs*32;          // wave's q-strip base

    bf16x8 aQ[8];
    {
      const long qrow = (long)bh*2048 + qw + ln;
#pragma unroll
      for (int ch=0; ch<8; ch++)
        aQ[ch] = *(const bf16x8*)(q + qrow*128 + ch*16 + h2*8);
    }
    f32x16 accO[4];
#pragma unroll
    for (int dt=0; dt<4; dt++)
#pragma unroll
      for (int r=0;r<16;r++) accO[dt][r] = 0.f;
    float lsum = 0.f;

    __syncthreads();                    // prior sub's LDS users done
    loadKV(0, 0);
    int cur = 0;
    const int ktMax = 2*qt + 1;

    for (int kt=0; kt<=ktMax; kt++){
      __syncthreads();                  // buf[cur] ready; buf[cur^1] readers done
      if (kt < ktMax) loadKV(kt+1, cur^1);

      const int key0 = kt*64 + kh*32;
      if (key0 <= qw + 31){             // not fully masked for this wave
        // S^T[key][q] 32x32: A = K-half, B = Q-strip
        f32x16 accS;
#pragma unroll
        for (int r=0;r<16;r++) accS[r] = 0.f;
        const int krow = kh*32 + ln;
#pragma unroll
        for (int ch=0; ch<8; ch++){
          bf16x8 ak = *(const bf16x8*)(lK + cur*8192 + krow*128 + (((ch*2+h2) ^ (krow&15))*8));
          accS = MFMA32(ak, aQ[ch], accS);
        }

        const bool diag = (key0 + 31 > qw);
        float pe[16];
        float ls0 = 0.f, ls1 = 0.f;
#pragma unroll
        for (int r=0;r<16;r++){
          float s = accS[r];
          if (diag){
            int keyg = key0 + (r&3) + 8*(r>>2) + 4*h2;
            if (keyg > qw + ln) s = -INFINITY;   // exp2(-inf) = 0
          }
          pe[r] = exp2f(s);
          if (r & 1) ls1 += pe[r]; else ls0 += pe[r];
        }
        lsum += ls0 + ls1;

        // P -> lP [q][key], b64 per reg-quad (keys contiguous)
        {
          u16* lpw = lP + qs*2048 + ln*64;
#pragma unroll
          for (int g=0; g<4; g++){
            uint2 w = make_uint2(pack2(pe[4*g], pe[4*g+1]), pack2(pe[4*g+2], pe[4*g+3]));
            *(uint2*)(lpw + (((kh*4+g) ^ (ln&7))*8) + h2*4) = w;
          }
        }

        // O[q][d] partial: A = P (own strip, own key-half), B = V^T
#pragma unroll
        for (int kk=0; kk<2; kk++){
          bf16x8 ap = *(const bf16x8*)(lP + qs*2048 + ln*64 + (((kh*4+kk*2+h2) ^ (ln&7))*8));
#pragma unroll
          for (int dt=0; dt<4; dt++){
            int vrow = dt*32 + ln;
            bf16x8 bv = *(const bf16x8*)(lV + cur*8192 + vrow*64 + (((kh*4+kk*2+h2) ^ (vrow&7))*8));
            accO[dt] = MFMA32(ap, bv, accO[dt]);
          }
        }
      }
      cur ^= 1;
    }

    // ---- epilogue: combine kh halves, normalize, store ----
    lsum += __shfl_xor(lsum, 32);       // fold h2 halves
    __syncthreads();                    // main-loop LDS reads done before alias reuse
    if (kh == 1){
#pragma unroll
      for (int dt=0; dt<4; dt++)
#pragma unroll
        for (int r=0;r<16;r++){
          int row = (r&3) + 8*(r>>2) + 4*h2;
          scrO[((qs*4+dt)*32 + row)*32 + ln] = accO[dt][r];
        }
      if (h2 == 0) scrL[128 + qs*32 + ln] = lsum;
    } else {
      if (h2 == 0) scrL[qs*32 + ln] = lsum;
    }
    __syncthreads();
    if (kh == 0){
      float linv[16];
#pragma unroll
      for (int r=0;r<16;r++){
        int row = (r&3) + 8*(r>>2) + 4*h2;
        linv[r] = 1.0f / (scrL[qs*32 + row] + scrL[128 + qs*32 + row]);
      }
      const int b = bh >> 3, h = bh & 7;
#pragma unroll
      for (int dt=0; dt<4; dt++){
#pragma unroll
        for (int r=0;r<16;r++){
          int row = (r&3) + 8*(r>>2) + 4*h2;
          float val = accO[dt][r] + scrO[((qs*4+dt)*32 + row)*32 + ln];
          int t = q0 + qs*32 + row;
          o[((long)(b*2048 + t))*1024 + h*128 + dt*32 + ln] = f2b(val * linv[r]);
        }
      }
    }
  }
}

// ---------------- output projection ----------------
__global__ __launch_bounds__(256) void gemm_out_k(
    const u16* __restrict__ oa, const u16* __restrict__ woT, float* __restrict__ out)
{
  f32x4 acc[4][4];
  const int rowBase = blockIdx.x*128, colBase = blockIdx.y*128;
  gemm128_bt(oa, woT, 1024, rowBase, colBase, acc);
  const int lane = threadIdx.x & 63, wave = threadIdx.x >> 6;
  const int wr = wave >> 1, wc = wave & 1;
  const int qd = lane >> 4, c = lane & 15;
#pragma unroll
  for (int mi=0;mi<4;mi++){
#pragma unroll
    for (int ni=0;ni<4;ni++){
      int row = rowBase + wr*64 + mi*16 + qd*4;
      int col = colBase + wc*64 + ni*16 + c;
#pragma unroll
      for (int r=0;r<4;r++)
        out[(size_t)(row+r)*1024 + col] = acc[mi][ni][r];
    }
  }
}

extern "C" void kernel_launch(void* const* d_in, const int* in_sizes, int n_in,
                              void* d_out, int out_size, void* d_ws, size_t ws_size,
                              hipStream_t stream) {
  const float* x  = (const float*)d_in[0];
  const float* wq = (const float*)d_in[1];
  const float* wk = (const float*)d_in[2];
  const float* wv = (const float*)d_in[3];
  const float* wo = (const float*)d_in[4];
  float* out = (float*)d_out;

  char* ws = (char*)d_ws;
  u16* xb    = (u16*)(ws);
  u16* wqkvT = (u16*)(ws + (16u<<20));
  u16* woT   = (u16*)(ws + (22u<<20));
  u16* qb    = (u16*)(ws + (24u<<20));
  u16* kb    = (u16*)(ws + (40u<<20));
  u16* vT    = (u16*)(ws + (56u<<20));
  u16* ob    = xb;   // reuse xb after gemm_qkv

  conv_k    <<<dim3(5120), dim3(256), 0, stream>>>(x, wq, wk, wv, wo, xb, wqkvT, woT);
  gemm_qkv_k<<<dim3(64,24), dim3(256), 0, stream>>>(xb, wqkvT, qb, kb, vT);
  attn_k    <<<dim3(32,8), dim3(512), 0, stream>>>(qb, kb, vT, ob);
  gemm_out_k<<<dim3(64,8),  dim3(256), 0, stream>>>(ob, woT, out);
}